// Round 2
// baseline (1035.011 us; speedup 1.0000x reference)
//
#include <hip/hip_runtime.h>
#include <hip/hip_bf16.h>

// Attention4DDownsample — fused, one workgroup per batch element.
// R6: 1024-thread blocks, 1 block/CU, 156 KB LDS. Eliminates the R5 register
// spill (242 MB phantom WRITE_SIZE): vsm has its own LDS region, so vGEMM
// accumulators (32 regs max) retire immediately. One-B-fragment-per-wave GEMM
// partition (3x fewer LDS reads), vectorized v_local, BN folded into float2
// table by prep kernel.

#define DIMC 384
#define NPOS 49
#define NHKD 128
#define DHC  512
#define OUTC 384

// ws bf16 weight offsets (elements)
#define OFF_KW  0
#define OFF_VW  49152
#define OFF_QPW 245760
#define OFF_PW  294912
#define W_TOT   491520
// BN fold table (float2, indexed after W_TOT bf16 elems): k,q,v,vl,p
#define BN_K  0
#define BN_Q  128
#define BN_V  256
#define BN_VL 768
#define BN_P  1280
#define BN_TOT 1664

// LDS regions (bf16 element offsets), total 78,088 elems = 156,176 B (1 block/CU)
#define XS_OFF   0        // xs [49][392]; rout [16][520] overlays after bar3
#define KT_OFF   19208    // kt [64][136] (rows <49 valid)
#define QSM_OFF  27912    // qsm [8][16][40] (kd 16..31 zeroed)
#define QIN_OFF  33032    // qin [16][392]; attnS [8][16][64] overlays after bar3
#define VSM_OFF  41224    // vsm [512][72]
#define SMEM_ELEMS 78088

typedef __attribute__((ext_vector_type(8))) __bf16 bf16x8;
typedef __attribute__((ext_vector_type(4))) float f32x4;

static __device__ __forceinline__ __hip_bfloat16 f2b(float x) { return __float2bfloat16(x); }
static __device__ __forceinline__ float b2f(__hip_bfloat16 x) { return __bfloat162float(x); }
static __device__ __forceinline__ bf16x8 ld8(const __hip_bfloat16* p) { return *(const bf16x8*)p; }
static __device__ __forceinline__ f32x4 fzero() {
  f32x4 z; z[0] = 0.f; z[1] = 0.f; z[2] = 0.f; z[3] = 0.f; return z;
}
static __device__ __forceinline__ bf16x8 bzero() {
  bf16x8 z;
  #pragma unroll
  for (int j = 0; j < 8; ++j) z[j] = (__bf16)0.0f;
  return z;
}

// ---------------- prep: fp32 weights -> bf16 in ws; BN fold -> float2 table ----------------
__global__ void prep_weights(const float* __restrict__ kw, const float* __restrict__ vw,
                             const float* __restrict__ qpw, const float* __restrict__ pw,
                             const float* __restrict__ kb,  const float* __restrict__ kbn,
                             const float* __restrict__ qpb, const float* __restrict__ qbn,
                             const float* __restrict__ vb,  const float* __restrict__ vbn,
                             const float* __restrict__ vlb, const float* __restrict__ vlbn,
                             const float* __restrict__ pb,  const float* __restrict__ pbn,
                             __hip_bfloat16* __restrict__ wsb) {
  const int gid = blockIdx.x * blockDim.x + threadIdx.x;
  const int stride = gridDim.x * blockDim.x;
  for (int i = gid; i < W_TOT; i += stride) {
    float v;
    if (i < OFF_VW)       v = kw[i - OFF_KW];
    else if (i < OFF_QPW) v = vw[i - OFF_VW];
    else if (i < OFF_PW)  v = qpw[i - OFF_QPW];
    else                  v = pw[i - OFF_PW];
    wsb[i] = f2b(v);
  }
  float2* bnt = (float2*)(wsb + W_TOT);
  for (int i = gid; i < BN_TOT; i += stride) {
    const float *bn, *cb; int ch, C;
    if (i < BN_Q)        { bn = kbn;  cb = kb;  ch = i;         C = NHKD; }
    else if (i < BN_V)   { bn = qbn;  cb = qpb; ch = i - BN_Q;  C = NHKD; }
    else if (i < BN_VL)  { bn = vbn;  cb = vb;  ch = i - BN_V;  C = DHC;  }
    else if (i < BN_P)   { bn = vlbn; cb = vlb; ch = i - BN_VL; C = DHC;  }
    else                 { bn = pbn;  cb = pb;  ch = i - BN_P;  C = OUTC; }
    const float g = bn[ch], be = bn[C + ch], mu = bn[2*C + ch], va = bn[3*C + ch];
    const float s = g * rsqrtf(va + 1e-5f);
    bnt[i] = make_float2(s, be + (cb[ch] - mu) * s);
  }
}

// ---------------- main fused kernel ----------------
__global__ __launch_bounds__(1024, 4) void attn4d_kernel(
    const float* __restrict__ x,
    const float* __restrict__ qlw, const float* __restrict__ qlb,
    const float* __restrict__ vlw,
    const float* __restrict__ ab,  const int* __restrict__ bidx,
    const __hip_bfloat16* __restrict__ wsb,
    int n_off, float* __restrict__ out)
{
  __shared__ __align__(16) __hip_bfloat16 smem[SMEM_ELEMS];
  __hip_bfloat16* xs    = smem + XS_OFF;     // [49][392]
  __hip_bfloat16* rout  = smem + XS_OFF;     // [16][520], overlays xs after bar3
  __hip_bfloat16* kt    = smem + KT_OFF;     // [64][136]
  __hip_bfloat16* qsm   = smem + QSM_OFF;    // [8][16][40]
  __hip_bfloat16* qin   = smem + QIN_OFF;    // [16][392]
  __hip_bfloat16* attnS = smem + QIN_OFF;    // [8][16][64] swizzled, after bar3
  __hip_bfloat16* vsm   = smem + VSM_OFF;    // [512][72]

  const __hip_bfloat16* kwb  = wsb + OFF_KW;
  const __hip_bfloat16* vwb  = wsb + OFF_VW;
  const __hip_bfloat16* qpwb = wsb + OFF_QPW;
  const __hip_bfloat16* pwb  = wsb + OFF_PW;
  const float2* bnt = (const float2*)(wsb + W_TOT);

  const int tid  = threadIdx.x;
  const int lane = tid & 63;
  const int wave = tid >> 6;     // 0..15
  const int quad = lane >> 4;    // 0..3
  const int l15  = lane & 15;
  const int b    = blockIdx.x;

  // ---- P0: stage x[b] (fp32 global) -> xs[n][c] bf16 transposed, b128 LDS writes
  {
    const float* xg = x + (size_t)b * (DIMC * NPOS);
    for (int j = tid; j < NPOS * (DIMC / 8); j += 1024) {   // 2352 jobs
      const int n  = j % 49;
      const int c0 = (j / 49) * 8;
      union { bf16x8 v; __hip_bfloat16 h[8]; } u;
      #pragma unroll
      for (int k = 0; k < 8; ++k)
        u.h[k] = f2b(xg[(c0 + k) * 49 + n]);
      *(bf16x8*)&xs[n * 392 + c0] = u.v;
    }
  }
  __syncthreads();   // bar1

  // ---- PA: qin[nq][c] = dw3x3 s2 p1 (local_q) + avgpool2; 768 threads, 2 oh rows each
  if (tid < 768) {
    const int part = tid >= 384;         // 0: oh{0,1}, rows n 0..27; 1: oh{2,3}, rows n 21..48
    const int c    = tid - part * 384;
    const int nb   = part * 21;
    float xv[28];
    #pragma unroll
    for (int i = 0; i < 28; ++i) xv[i] = b2f(xs[(nb + i) * 392 + c]);
    float wq[9];
    #pragma unroll
    for (int j = 0; j < 9; ++j) wq[j] = qlw[c * 9 + j];
    const float cb = qlb[c];
    #pragma unroll
    for (int ohh = 0; ohh < 2; ++ohh) {
      const int oh = part * 2 + ohh;
      #pragma unroll
      for (int ow = 0; ow < 4; ++ow) {
        float a = cb;
        #pragma unroll
        for (int kh = 0; kh < 3; ++kh) {
          const int ih = 2 * oh - 1 + kh;
          if (ih < 0 || ih > 6) continue;
          #pragma unroll
          for (int kwi = 0; kwi < 3; ++kwi) {
            const int iw = 2 * ow - 1 + kwi;
            if (iw < 0 || iw > 6) continue;
            a += wq[kh * 3 + kwi] * xv[ih * 7 + iw - nb];
          }
        }
        if (oh < 3 && ow < 3)
          a += 0.25f * (xv[(2*oh)*7 + 2*ow - nb]   + xv[(2*oh)*7 + 2*ow + 1 - nb] +
                        xv[(2*oh+1)*7 + 2*ow - nb] + xv[(2*oh+1)*7 + 2*ow + 1 - nb]);
        qin[(oh * 4 + ow) * 392 + c] = f2b(a);
      }
    }
  }
  __syncthreads();   // bar2

  // ================= GEMM phase: k + q + v, one B-fragment per wave =================

  // -- k GEMM: wave = (nt = w&3, mtp = w>>2 -> M-tiles {2mtp, 2mtp+1}), K=384
  {
    const int nt  = wave & 3;
    const int mtp = wave >> 2;
    const int n   = nt * 16 + l15;
    f32x4 acc[2]; acc[0] = fzero(); acc[1] = fzero();
    for (int ks = 0; ks < 12; ++ks) {
      const int c0 = ks * 32 + quad * 8;
      bf16x8 z = (n < 49) ? ld8(&xs[n * 392 + c0]) : bzero();
      #pragma unroll
      for (int i = 0; i < 2; ++i) {
        bf16x8 a = ld8(&kwb[((mtp * 2 + i) * 16 + l15) * DIMC + c0]);
        acc[i] = __builtin_amdgcn_mfma_f32_16x16x32_bf16(a, z, acc[i], 0, 0, 0);
      }
    }
    #pragma unroll
    for (int i = 0; i < 2; ++i)
      #pragma unroll
      for (int r = 0; r < 4; ++r) {
        const int oc = (mtp * 2 + i) * 16 + quad * 4 + r;
        const float2 so = bnt[BN_K + oc];
        if (n < 49) kt[n * 136 + oc] = f2b(acc[i][r] * so.x + so.y);
      }
  }

  // -- q GEMM (waves 0..7): head h = wave, out -> qsm with zeroed kd16..31 pad
  if (wave < 8) {
    const int mt = wave;
    f32x4 acc = fzero();
    for (int ks = 0; ks < 12; ++ks) {
      const int c0 = ks * 32 + quad * 8;
      bf16x8 bv = ld8(&qin[l15 * 392 + c0]);
      bf16x8 av = ld8(&qpwb[(mt * 16 + l15) * DIMC + c0]);
      acc = __builtin_amdgcn_mfma_f32_16x16x32_bf16(av, bv, acc, 0, 0, 0);
    }
    #pragma unroll
    for (int r = 0; r < 4; ++r) {
      const int oc = mt * 16 + quad * 4 + r;
      const float2 so = bnt[BN_Q + oc];
      const int kd = oc & 15;
      qsm[wave * 640 + l15 * 40 + kd] = f2b(acc[r] * so.x + so.y);
      qsm[wave * 640 + l15 * 40 + kd + 16] = f2b(0.f);
    }
  }

  // -- v GEMM: wave = (nt = w>>2, mgrp = w&3 -> 8 M-tiles), 32 acc regs, retire to vsm
  {
    const int nt   = wave >> 2;
    const int mgrp = wave & 3;
    const int n    = nt * 16 + l15;
    f32x4 va[8];
    #pragma unroll
    for (int i = 0; i < 8; ++i) va[i] = fzero();
    for (int ks = 0; ks < 12; ++ks) {
      const int c0 = ks * 32 + quad * 8;
      bf16x8 z = (n < 49) ? ld8(&xs[n * 392 + c0]) : bzero();
      #pragma unroll
      for (int i = 0; i < 8; ++i) {
        bf16x8 a = ld8(&vwb[((mgrp * 8 + i) * 16 + l15) * DIMC + c0]);
        va[i] = __builtin_amdgcn_mfma_f32_16x16x32_bf16(a, z, va[i], 0, 0, 0);
      }
    }
    #pragma unroll
    for (int i = 0; i < 8; ++i)
      #pragma unroll
      for (int r = 0; r < 4; ++r) {
        const int ch = (mgrp * 8 + i) * 16 + quad * 4 + r;
        const float2 so = bnt[BN_V + ch];
        // write ALL n incl. pads (finite) — PV multiplies pads by attn==0
        vsm[ch * 72 + n] = f2b(va[i][r] * so.x + so.y);
      }
  }
  __syncthreads();   // bar3 — xs dead; kt/qsm/vsm ready

  // ---- PD (waves 8..15, h = wave-8): QK^T*scale + bias, softmax -> attnS (swizzled)
  if (wave >= 8) {
    const int h = wave - 8;
    bf16x8 av = ld8(&qsm[h * 640 + l15 * 40 + quad * 8]);
    float p[4][4];
    #pragma unroll
    for (int t = 0; t < 4; ++t) {
      bf16x8 bv = bzero();
      if (quad < 2) bv = ld8(&kt[(t * 16 + l15) * 136 + h * 16 + quad * 8]);
      f32x4 lg = __builtin_amdgcn_mfma_f32_16x16x32_bf16(av, bv, fzero(), 0, 0, 0);
      #pragma unroll
      for (int r = 0; r < 4; ++r) {
        const int nq = quad * 4 + r;
        const int nk = t * 16 + l15;
        float val = -30000.f;
        if (nk < 49) val = lg[r] * 0.25f + ab[h * n_off + bidx[nq * 49 + nk]];
        p[t][r] = val;
      }
    }
    #pragma unroll
    for (int r = 0; r < 4; ++r) {
      float m = fmaxf(fmaxf(p[0][r], p[1][r]), fmaxf(p[2][r], p[3][r]));
      m = fmaxf(m, __shfl_xor(m, 1));
      m = fmaxf(m, __shfl_xor(m, 2));
      m = fmaxf(m, __shfl_xor(m, 4));
      m = fmaxf(m, __shfl_xor(m, 8));
      float e[4], sum = 0.f;
      #pragma unroll
      for (int t = 0; t < 4; ++t) { e[t] = __expf(p[t][r] - m); sum += e[t]; }
      sum += __shfl_xor(sum, 1);
      sum += __shfl_xor(sum, 2);
      sum += __shfl_xor(sum, 4);
      sum += __shfl_xor(sum, 8);
      const float inv = 1.f / sum;
      #pragma unroll
      for (int t = 0; t < 4; ++t) p[t][r] = e[t] * inv;   // exactly 0 for nk>=49
    }
    #pragma unroll
    for (int r = 0; r < 4; ++r) {
      const int nq = quad * 4 + r;
      #pragma unroll
      for (int t = 0; t < 4; ++t) {
        const int nk = t * 16 + l15;
        attnS[h * 1024 + nq * 64 + (nk ^ ((nq & 7) << 3))] = f2b(p[t][r]);
      }
    }
  }

  // ---- v_local (all waves, ch = 32w..32w+31): vectorized row load, write rout
  {
    const int cl   = lane & 31;
    const int half = lane >> 5;
    const int gch  = wave * 32 + cl;
    const __hip_bfloat16* vrow = vsm + gch * 72;
    bf16x8 rv[7];
    #pragma unroll
    for (int t = 0; t < 7; ++t) rv[t] = ld8(vrow + t * 8);
    float wv[9];
    #pragma unroll
    for (int j = 0; j < 9; ++j) wv[j] = vlw[gch * 9 + j];
    const float2 so = bnt[BN_VL + gch];
    #pragma unroll
    for (int pp = 0; pp < 8; ++pp) {
      const int pos = half * 8 + pp;
      const int oh = pos >> 2, ow = pos & 3;
      float a = 0.f;
      #pragma unroll
      for (int kh = 0; kh < 3; ++kh) {
        const int ih = 2 * oh - 1 + kh;
        if (ih < 0 || ih > 6) continue;
        #pragma unroll
        for (int kwi = 0; kwi < 3; ++kwi) {
          const int iw = 2 * ow - 1 + kwi;
          if (iw < 0 || iw > 6) continue;
          const int e = ih * 7 + iw;      // 0..48, compile-time after unroll
          a += wv[kh * 3 + kwi] * (float)rv[e >> 3][e & 7];
        }
      }
      rout[pos * 520 + gch] = f2b(a * so.x + so.y);
    }
  }
  __syncthreads();   // bar4 — attnS + rout(v_local) ready

  // ---- PV: wave w owns ch 32w..32w+31, head h = w>>1; rout = relu(xa + vloc)
  {
    const int h   = wave >> 1;
    const int ch0 = wave * 32;
    f32x4 pacc[2]; pacc[0] = fzero(); pacc[1] = fzero();
    #pragma unroll
    for (int mt2 = 0; mt2 < 2; ++mt2)
      #pragma unroll
      for (int ks = 0; ks < 2; ++ks) {
        const int k0 = ks * 32 + quad * 8;
        bf16x8 avv = ld8(&vsm[(ch0 + mt2 * 16 + l15) * 72 + k0]);            // A[ch][nk]
        bf16x8 bvv = ld8(&attnS[h * 1024 + l15 * 64 + (k0 ^ ((l15 & 7) << 3))]); // B[nq][nk]
        pacc[mt2] = __builtin_amdgcn_mfma_f32_16x16x32_bf16(avv, bvv, pacc[mt2], 0, 0, 0);
      }
    #pragma unroll
    for (int mt2 = 0; mt2 < 2; ++mt2)
      #pragma unroll
      for (int r = 0; r < 4; ++r) {
        const int ch = ch0 + mt2 * 16 + quad * 4 + r;
        const int ad = l15 * 520 + ch;
        const float val = pacc[mt2][r] + b2f(rout[ad]);
        rout[ad] = f2b(fmaxf(val, 0.f));
      }
  }
  __syncthreads();   // bar5 — rout complete

  // ---- PF: proj GEMM — 24 M-tiles over 16 waves (waves 0..7 take 2)
  {
    f32x4 acc[2]; acc[0] = fzero(); acc[1] = fzero();
    for (int ks = 0; ks < 16; ++ks) {
      const int c0 = ks * 32 + quad * 8;
      bf16x8 bv = ld8(&rout[l15 * 520 + c0]);
      bf16x8 av = ld8(&pwb[(wave * 16 + l15) * DHC + c0]);
      acc[0] = __builtin_amdgcn_mfma_f32_16x16x32_bf16(av, bv, acc[0], 0, 0, 0);
      if (wave < 8) {
        bf16x8 av2 = ld8(&pwb[((16 + wave) * 16 + l15) * DHC + c0]);
        acc[1] = __builtin_amdgcn_mfma_f32_16x16x32_bf16(av2, bv, acc[1], 0, 0, 0);
      }
    }
    float* outb = out + (size_t)b * (OUTC * 16);
    #pragma unroll
    for (int r = 0; r < 4; ++r) {
      const int oc = wave * 16 + quad * 4 + r;
      const float2 so = bnt[BN_P + oc];
      outb[oc * 16 + l15] = acc[0][r] * so.x + so.y;
    }
    if (wave < 8) {
      #pragma unroll
      for (int r = 0; r < 4; ++r) {
        const int oc = (16 + wave) * 16 + quad * 4 + r;
        const float2 so = bnt[BN_P + oc];
        outb[oc * 16 + l15] = acc[1][r] * so.x + so.y;
      }
    }
  }
}

extern "C" void kernel_launch(void* const* d_in, const int* in_sizes, int n_in,
                              void* d_out, int out_size, void* d_ws, size_t ws_size,
                              hipStream_t stream) {
  const float* x    = (const float*)d_in[0];
  const float* qlw  = (const float*)d_in[1];
  const float* qlb  = (const float*)d_in[2];
  const float* qpw  = (const float*)d_in[3];
  const float* qpb  = (const float*)d_in[4];
  const float* qbn  = (const float*)d_in[5];
  const float* kw   = (const float*)d_in[6];
  const float* kb   = (const float*)d_in[7];
  const float* kbn  = (const float*)d_in[8];
  const float* vw   = (const float*)d_in[9];
  const float* vb   = (const float*)d_in[10];
  const float* vbn  = (const float*)d_in[11];
  const float* vlw  = (const float*)d_in[12];
  const float* vlb  = (const float*)d_in[13];
  const float* vlbn = (const float*)d_in[14];
  const float* pw   = (const float*)d_in[15];
  const float* pb   = (const float*)d_in[16];
  const float* pbn  = (const float*)d_in[17];
  const float* ab   = (const float*)d_in[18];
  const int*   bidx = (const int*)d_in[19];
  const int n_off = in_sizes[18] / 8;
  const int Bn = in_sizes[0] / (DIMC * NPOS);   // 2048

  __hip_bfloat16* wsb = (__hip_bfloat16*)d_ws;  // 983,040 B weights + 13,312 B BN table

  prep_weights<<<480, 256, 0, stream>>>(kw, vw, qpw, pw,
                                        kb, kbn, qpb, qbn, vb, vbn,
                                        vlb, vlbn, pb, pbn, wsb);
  attn4d_kernel<<<Bn, 1024, 0, stream>>>(x, qlw, qlb, vlw, ab, bidx,
                                         wsb, n_off, (float*)d_out);
}